// Round 1
// baseline (4795.521 us; speedup 1.0000x reference)
//
#include <hip/hip_runtime.h>
#include <hip/hip_bf16.h>

typedef __bf16 bf16_t;
typedef __bf16 bf16x8 __attribute__((ext_vector_type(8)));
typedef float f32x4 __attribute__((ext_vector_type(4)));

#define SEQLEN 256
#define NBATCH 64
#define INDIM  512
#define HID    1024
#define NGATE  4096
#define NBLK   128

// workspace layout (bytes)
#define XG_OFF   0ull                // bf16 [16384][4096]  = 134217728
#define XBF_OFF  134217728ull        // bf16 [16384][512]   = 16777216
#define WX_OFF   150994944ull        // bf16 [4096][512]    = 4194304
#define WH_OFF   155189248ull        // bf16 [4096][1024]   = 8388608
#define BS_OFF   163577856ull        // f32  [4096]         = 16384
#define HBF_OFF  163594240ull        // bf16 [2][64][1024]  = 262144
#define CTR_OFF  163856384ull        // int barrier counter

__device__ __forceinline__ bf16x8 cvt8(float4 a, float4 b) {
  bf16x8 v;
  v[0] = (bf16_t)a.x; v[1] = (bf16_t)a.y; v[2] = (bf16_t)a.z; v[3] = (bf16_t)a.w;
  v[4] = (bf16_t)b.x; v[5] = (bf16_t)b.y; v[6] = (bf16_t)b.z; v[7] = (bf16_t)b.w;
  return v;
}

// ---------------- pack x -> bf16 ----------------
__global__ __launch_bounds__(256) void pack_x_k(const float* __restrict__ x,
                                                bf16_t* __restrict__ xb) {
  int idx = blockIdx.x * 256 + threadIdx.x;       // 0 .. 1048575, 8 elems each
  const float4* s = (const float4*)x + (size_t)idx * 2;
  float4 a = s[0], b = s[1];
  *(bf16x8*)(xb + (size_t)idx * 8) = cvt8(a, b);
}

// ---------------- pack weights (gate-permuted rows) + bias sums ----------------
struct GatePtrs {
  const float* Wi[4];
  const float* bi[4];
  const float* Wh[4];
  const float* bh[4];
};

__global__ __launch_bounds__(256) void pack_w_k(GatePtrs p,
                                                bf16_t* __restrict__ Wx,
                                                bf16_t* __restrict__ Wh,
                                                float* __restrict__ bsum) {
  int idx = blockIdx.x * 256 + threadIdx.x;       // 0 .. 786431
  int row = idx / 192;                            // n_packed, 0..4095
  int c   = idx % 192;
  int blk = row >> 5, r = row & 31, g = r >> 3, jj = r & 7;
  int j = blk * 8 + jj;                           // original hidden index
  if (c == 0) bsum[row] = p.bi[g][j] + p.bh[g][j];
  if (c < 64) {
    const float4* s = (const float4*)(p.Wi[g] + (size_t)j * INDIM + c * 8);
    *(bf16x8*)(Wx + (size_t)row * INDIM + c * 8) = cvt8(s[0], s[1]);
  } else {
    int cc = c - 64;
    const float4* s = (const float4*)(p.Wh[g] + (size_t)j * HID + cc * 8);
    *(bf16x8*)(Wh + (size_t)row * HID + cc * 8) = cvt8(s[0], s[1]);
  }
}

// ---------------- phase 1: xg = x @ Wx^T + bsum (bf16 out) ----------------
__global__ __launch_bounds__(256) void gemm_xproj_k(const bf16_t* __restrict__ A,
                                                    const bf16_t* __restrict__ B,
                                                    const float* __restrict__ bsum,
                                                    bf16_t* __restrict__ C) {
  __shared__ bf16_t As[128 * 32];
  __shared__ bf16_t Bs[128 * 32];
  const int tid = threadIdx.x, w = tid >> 6, l = tid & 63;
  const int m0 = blockIdx.y * 128, n0 = blockIdx.x * 128;
  const int wr = (w >> 1) * 64, wc = (w & 1) * 64;
  const int kg = (l >> 4) * 8, rr = l & 15;
  f32x4 acc[4][4] = {};

  const int segrow = l >> 2, segk = (l & 3) * 8;
  for (int k0 = 0; k0 < INDIM; k0 += 32) {
    __syncthreads();   // previous tile's readers done
#pragma unroll
    for (int i = 0; i < 2; ++i) {
      int seg = w * 2 + i;
      const bf16_t* ga = A + (size_t)(m0 + seg * 16 + segrow) * INDIM + k0 + segk;
      __builtin_amdgcn_global_load_lds((const __attribute__((address_space(1))) void*)ga,
                                       (__attribute__((address_space(3))) void*)(As + seg * 512),
                                       16, 0, 0);
      const bf16_t* gb = B + (size_t)(n0 + seg * 16 + segrow) * INDIM + k0 + segk;
      __builtin_amdgcn_global_load_lds((const __attribute__((address_space(1))) void*)gb,
                                       (__attribute__((address_space(3))) void*)(Bs + seg * 512),
                                       16, 0, 0);
    }
    __syncthreads();   // staging complete (vmcnt drained at barrier)
    bf16x8 af[4], bfr[4];
#pragma unroll
    for (int mi = 0; mi < 4; ++mi) af[mi]  = *(const bf16x8*)(As + (wr + mi * 16 + rr) * 32 + kg);
#pragma unroll
    for (int ni = 0; ni < 4; ++ni) bfr[ni] = *(const bf16x8*)(Bs + (wc + ni * 16 + rr) * 32 + kg);
#pragma unroll
    for (int mi = 0; mi < 4; ++mi)
#pragma unroll
      for (int ni = 0; ni < 4; ++ni)
        acc[mi][ni] = __builtin_amdgcn_mfma_f32_16x16x32_bf16(af[mi], bfr[ni], acc[mi][ni], 0, 0, 0);
  }
  const int ri = (l >> 4) * 4;
#pragma unroll
  for (int ni = 0; ni < 4; ++ni) {
    int n = n0 + wc + ni * 16 + rr;
    float bs = bsum[n];
#pragma unroll
    for (int mi = 0; mi < 4; ++mi) {
      int mbase = m0 + wr + mi * 16 + ri;
#pragma unroll
      for (int r = 0; r < 4; ++r)
        C[(size_t)(mbase + r) * NGATE + n] = (bf16_t)(acc[mi][ni][r] + bs);
    }
  }
}

// ---------------- phase 2: persistent recurrence ----------------
__global__ __launch_bounds__(256, 1) void lstm_rec_k(const bf16_t* __restrict__ Wh,
                                                     const bf16_t* __restrict__ xg,
                                                     bf16_t* __restrict__ hbf,
                                                     float* __restrict__ out,
                                                     int* __restrict__ ctr) {
  const int b = blockIdx.x;              // 0..127: owns h-cols [b*8, b*8+8)
  const int tid = threadIdx.x;
  const int w = tid >> 6, l = tid & 63;
  const int kw = w >> 1, nw = w & 1;     // K-half, N-tile
  const int arow = l & 15, kg = (l >> 4) * 8;

  __shared__ bf16_t Wt[32 * 1024];       // 64 KB, XOR-swizzled rows
  __shared__ float  pre[2][32][68];      // [kw][gate-row][batch], padded
  __shared__ bf16_t xgs[2][64 * 32];     // xg slab ping-pong

  // --- load weight slab into LDS (swizzled) ---
  for (int idx = tid; idx < 4096; idx += 256) {
    int r = idx >> 7;            // 0..31
    int c = idx & 127;           // 8-elem chunk
    bf16x8 v = *(const bf16x8*)(Wh + (size_t)(b * 32 + r) * HID + c * 8);
    *(bf16x8*)((char*)Wt + r * 2048 + ((c * 16) ^ ((r & 7) << 4))) = v;
  }
  // --- prefetch xg for t=0 ---
  {
    int batch = tid >> 2, c = tid & 3;
    bf16x8 v = *(const bf16x8*)(xg + (size_t)batch * NGATE + b * 32 + c * 8);
    *(bf16x8*)(xgs[0] + batch * 32 + c * 8) = v;
  }
  __syncthreads();

  // cell state: thread owns (ebatch, ejj) and (ebatch+32, ejj)
  const int ebatch = tid >> 3, ejj = tid & 7;
  float c0 = 0.f, c1 = 0.f;

  for (int t = 0; t < SEQLEN; ++t) {
    // prefetch next xg slab into regs (hidden under the K-loop)
    bf16x8 xnext;
    if (t < SEQLEN - 1) {
      int batch = tid >> 2, c = tid & 3;
      xnext = *(const bf16x8*)(xg + (size_t)(t + 1) * NBATCH * NGATE + (size_t)batch * NGATE + b * 32 + c * 8);
    }

    const bf16_t* hp = hbf + (size_t)(t & 1) * (NBATCH * HID);
    f32x4 acc[4] = {};
    const int kbase = kw * 512;

    bf16x8 a_cur[4], a_nxt[4];
#pragma unroll
    for (int mi = 0; mi < 4; ++mi)
      a_cur[mi] = *(const bf16x8*)(hp + (size_t)(mi * 16 + arow) * HID + kbase + kg);

    const int brow = nw * 16 + arow;
    for (int kk = 0; kk < 16; ++kk) {
      int kb = kbase + kk * 32;
      if (kk < 15) {
#pragma unroll
        for (int mi = 0; mi < 4; ++mi)
          a_nxt[mi] = *(const bf16x8*)(hp + (size_t)(mi * 16 + arow) * HID + kb + 32 + kg);
      }
      bf16x8 bfr = *(const bf16x8*)((const char*)Wt + brow * 2048 + (((kb + kg) << 1) ^ ((brow & 7) << 4)));
#pragma unroll
      for (int mi = 0; mi < 4; ++mi)
        acc[mi] = __builtin_amdgcn_mfma_f32_16x16x32_bf16(a_cur[mi], bfr, acc[mi], 0, 0, 0);
      if (kk < 15) {
#pragma unroll
        for (int mi = 0; mi < 4; ++mi) a_cur[mi] = a_nxt[mi];
      }
    }

    // partial sums -> LDS
#pragma unroll
    for (int mi = 0; mi < 4; ++mi) {
      int batch0 = mi * 16 + (l >> 4) * 4;
      *(f32x4*)&pre[kw][nw * 16 + arow][batch0] = acc[mi];
    }
    // stage next xg slab
    if (t < SEQLEN - 1) {
      int batch = tid >> 2, c = tid & 3;
      *(bf16x8*)(xgs[(t + 1) & 1] + batch * 32 + c * 8) = xnext;
    }
    __syncthreads();

    // fused elementwise gate update (2 items per thread)
    const bf16_t* xr = xgs[t & 1];
#pragma unroll
    for (int it = 0; it < 2; ++it) {
      int batch = ebatch + it * 32;
      float pf = pre[0][ejj][batch]      + pre[1][ejj][batch]      + (float)xr[batch * 32 + ejj];
      float pi = pre[0][8 + ejj][batch]  + pre[1][8 + ejj][batch]  + (float)xr[batch * 32 + 8 + ejj];
      float po = pre[0][16 + ejj][batch] + pre[1][16 + ejj][batch] + (float)xr[batch * 32 + 16 + ejj];
      float pc = pre[0][24 + ejj][batch] + pre[1][24 + ejj][batch] + (float)xr[batch * 32 + 24 + ejj];
      float fg = 1.f / (1.f + __expf(-pf));
      float ig = 1.f / (1.f + __expf(-pi));
      float og = 1.f / (1.f + __expf(-po));
      float e2 = __expf(-2.f * fabsf(pc));
      float gg = __builtin_copysignf((1.f - e2) / (1.f + e2), pc);
      float& cs = it ? c1 : c0;
      cs = fg * cs + ig * gg;
      float e2c = __expf(-2.f * fabsf(cs));
      float th = __builtin_copysignf((1.f - e2c) / (1.f + e2c), cs);
      float hv = og * th;
      int j = b * 8 + ejj;
      out[((size_t)t * NBATCH + batch) * HID + j] = hv;
      hbf[(size_t)((t + 1) & 1) * (NBATCH * HID) + (size_t)batch * HID + j] = (bf16_t)hv;
      if (t == SEQLEN - 1) {
        out[(size_t)SEQLEN * NBATCH * HID + (size_t)batch * HID + j] = hv;                  // h_fin
        out[(size_t)SEQLEN * NBATCH * HID + (size_t)NBATCH * HID + (size_t)batch * HID + j] = cs; // c_fin
      }
    }

    // grid-wide barrier (monotonic counter; agent-scope fences for cross-XCD L2)
    if (t < SEQLEN - 1) {
      __syncthreads();                       // all waves' stores drained (vmcnt before s_barrier)
      if (tid == 0) {
        __threadfence();                     // release: L2 writeback
        __hip_atomic_fetch_add(ctr, 1, __ATOMIC_RELAXED, __HIP_MEMORY_SCOPE_AGENT);
        int target = NBLK * (t + 1);
        while (__hip_atomic_load(ctr, __ATOMIC_RELAXED, __HIP_MEMORY_SCOPE_AGENT) < target)
          __builtin_amdgcn_s_sleep(1);
        __threadfence();                     // acquire: L1/L2 invalidate
      }
      __syncthreads();
    }
  }
}

extern "C" void kernel_launch(void* const* d_in, const int* in_sizes, int n_in,
                              void* d_out, int out_size, void* d_ws, size_t ws_size,
                              hipStream_t stream) {
  (void)in_sizes; (void)n_in; (void)out_size; (void)ws_size;
  char* ws = (char*)d_ws;
  bf16_t* xg  = (bf16_t*)(ws + XG_OFF);
  bf16_t* xbf = (bf16_t*)(ws + XBF_OFF);
  bf16_t* Wx  = (bf16_t*)(ws + WX_OFF);
  bf16_t* Wh  = (bf16_t*)(ws + WH_OFF);
  float*  bs  = (float*)(ws + BS_OFF);
  bf16_t* hbf = (bf16_t*)(ws + HBF_OFF);
  int*    ctr = (int*)(ws + CTR_OFF);

  const float* x = (const float*)d_in[0];
  GatePtrs p;
  for (int g = 0; g < 4; ++g) {
    p.Wi[g] = (const float*)d_in[1 + 4 * g];
    p.bi[g] = (const float*)d_in[2 + 4 * g];
    p.Wh[g] = (const float*)d_in[3 + 4 * g];
    p.bh[g] = (const float*)d_in[4 + 4 * g];
  }

  hipMemsetAsync(hbf, 0, 2 * NBATCH * HID * sizeof(bf16_t) / 1, stream); // zero both h ping-pong bufs
  hipMemsetAsync(ctr, 0, 64, stream);
  pack_x_k<<<4096, 256, 0, stream>>>(x, xbf);
  pack_w_k<<<3072, 256, 0, stream>>>(p, Wx, Wh, bs);
  gemm_xproj_k<<<dim3(32, 128), 256, 0, stream>>>(xbf, Wx, bs, xg);
  lstm_rec_k<<<NBLK, 256, 0, stream>>>(Wh, xg, hbf, (float*)d_out, ctr);
}

// Round 2
// 2965.368 us; speedup vs baseline: 1.6172x; 1.6172x over previous
//
#include <hip/hip_runtime.h>
#include <hip/hip_bf16.h>

typedef __bf16 bf16_t;
typedef __bf16 bf16x8 __attribute__((ext_vector_type(8)));
typedef float f32x4 __attribute__((ext_vector_type(4)));

#define SEQLEN 256
#define NBATCH 64
#define INDIM  512
#define HID    1024
#define NGATE  4096
#define NBLK   128

// workspace layout (bytes)
#define XG_OFF   0ull                // bf16 [16384][4096]  = 134217728
#define XBF_OFF  134217728ull        // bf16 [16384][512]   = 16777216
#define WX_OFF   150994944ull        // bf16 [4096][512]    = 4194304
#define WH_OFF   155189248ull        // bf16 [4096][1024]   = 8388608
#define BS_OFF   163577856ull        // f32  [4096]         = 16384
#define HBF_OFF  163594240ull        // bf16 [2][64][1024]  = 262144 (h ping-pong, dword-atomic written)
#define CTR_OFF  163856384ull        // int barrier counter

__device__ __forceinline__ bf16x8 cvt8(float4 a, float4 b) {
  bf16x8 v;
  v[0] = (bf16_t)a.x; v[1] = (bf16_t)a.y; v[2] = (bf16_t)a.z; v[3] = (bf16_t)a.w;
  v[4] = (bf16_t)b.x; v[5] = (bf16_t)b.y; v[6] = (bf16_t)b.z; v[7] = (bf16_t)b.w;
  return v;
}

// ---------------- pack x -> bf16 ----------------
__global__ __launch_bounds__(256) void pack_x_k(const float* __restrict__ x,
                                                bf16_t* __restrict__ xb) {
  int idx = blockIdx.x * 256 + threadIdx.x;       // 8 elems each
  const float4* s = (const float4*)x + (size_t)idx * 2;
  float4 a = s[0], b = s[1];
  *(bf16x8*)(xb + (size_t)idx * 8) = cvt8(a, b);
}

// ---------------- pack weights (gate-permuted rows) + bias sums ----------------
struct GatePtrs {
  const float* Wi[4];
  const float* bi[4];
  const float* Wh[4];
  const float* bh[4];
};

__global__ __launch_bounds__(256) void pack_w_k(GatePtrs p,
                                                bf16_t* __restrict__ Wx,
                                                bf16_t* __restrict__ Wh,
                                                float* __restrict__ bsum) {
  int idx = blockIdx.x * 256 + threadIdx.x;       // 0 .. 786431
  int row = idx / 192;                            // n_packed, 0..4095
  int c   = idx % 192;
  int blk = row >> 5, r = row & 31, g = r >> 3, jj = r & 7;
  int j = blk * 8 + jj;                           // original hidden index
  if (c == 0) bsum[row] = p.bi[g][j] + p.bh[g][j];
  if (c < 64) {
    const float4* s = (const float4*)(p.Wi[g] + (size_t)j * INDIM + c * 8);
    *(bf16x8*)(Wx + (size_t)row * INDIM + c * 8) = cvt8(s[0], s[1]);
  } else {
    int cc = c - 64;
    const float4* s = (const float4*)(p.Wh[g] + (size_t)j * HID + cc * 8);
    *(bf16x8*)(Wh + (size_t)row * HID + cc * 8) = cvt8(s[0], s[1]);
  }
}

// ---------------- phase 1: xg = x @ Wx^T + bsum (bf16 out) ----------------
__global__ __launch_bounds__(256) void gemm_xproj_k(const bf16_t* __restrict__ A,
                                                    const bf16_t* __restrict__ B,
                                                    const float* __restrict__ bsum,
                                                    bf16_t* __restrict__ C) {
  __shared__ bf16_t As[128 * 32];
  __shared__ bf16_t Bs[128 * 32];
  const int tid = threadIdx.x, w = tid >> 6, l = tid & 63;
  const int m0 = blockIdx.y * 128, n0 = blockIdx.x * 128;
  const int wr = (w >> 1) * 64, wc = (w & 1) * 64;
  const int kg = (l >> 4) * 8, rr = l & 15;
  f32x4 acc[4][4] = {};

  const int segrow = l >> 2, segk = (l & 3) * 8;
  for (int k0 = 0; k0 < INDIM; k0 += 32) {
    __syncthreads();
#pragma unroll
    for (int i = 0; i < 2; ++i) {
      int seg = w * 2 + i;
      const bf16_t* ga = A + (size_t)(m0 + seg * 16 + segrow) * INDIM + k0 + segk;
      __builtin_amdgcn_global_load_lds((const __attribute__((address_space(1))) void*)ga,
                                       (__attribute__((address_space(3))) void*)(As + seg * 512),
                                       16, 0, 0);
      const bf16_t* gb = B + (size_t)(n0 + seg * 16 + segrow) * INDIM + k0 + segk;
      __builtin_amdgcn_global_load_lds((const __attribute__((address_space(1))) void*)gb,
                                       (__attribute__((address_space(3))) void*)(Bs + seg * 512),
                                       16, 0, 0);
    }
    __syncthreads();
    bf16x8 af[4], bfr[4];
#pragma unroll
    for (int mi = 0; mi < 4; ++mi) af[mi]  = *(const bf16x8*)(As + (wr + mi * 16 + rr) * 32 + kg);
#pragma unroll
    for (int ni = 0; ni < 4; ++ni) bfr[ni] = *(const bf16x8*)(Bs + (wc + ni * 16 + rr) * 32 + kg);
#pragma unroll
    for (int mi = 0; mi < 4; ++mi)
#pragma unroll
      for (int ni = 0; ni < 4; ++ni)
        acc[mi][ni] = __builtin_amdgcn_mfma_f32_16x16x32_bf16(af[mi], bfr[ni], acc[mi][ni], 0, 0, 0);
  }
  const int ri = (l >> 4) * 4;
#pragma unroll
  for (int ni = 0; ni < 4; ++ni) {
    int n = n0 + wc + ni * 16 + rr;
    float bs = bsum[n];
#pragma unroll
    for (int mi = 0; mi < 4; ++mi) {
      int mbase = m0 + wr + mi * 16 + ri;
#pragma unroll
      for (int r = 0; r < 4; ++r)
        C[(size_t)(mbase + r) * NGATE + n] = (bf16_t)(acc[mi][ni][r] + bs);
    }
  }
}

// ---------------- phase 2: persistent recurrence ----------------
// 128 blocks x 512 threads. Block b owns gate-rows [b*32, b*32+32) == h columns [b*8, b*8+8).
// 8 waves: kw = w>>1 in 0..3 (K slice of 256), nw = w&1 (16 gate-rows each).
// h published write-through via agent-scope dword atomics (no wbl2); acquire = buffer_inv only.
__global__ __launch_bounds__(512, 1) void lstm_rec_k(const bf16_t* __restrict__ Wh,
                                                     const bf16_t* __restrict__ xg,
                                                     unsigned int* __restrict__ hring,
                                                     float* __restrict__ out,
                                                     int* __restrict__ ctr) {
  const int b = blockIdx.x;
  const int tid = threadIdx.x;
  const int w = tid >> 6, l = tid & 63;
  const int kw = w >> 1, nw = w & 1;
  const int arow = l & 15, kg = (l >> 4) * 8;
  const int kbase = kw * 256;
  const int brow = nw * 16 + arow;

  __shared__ bf16_t Wt[32 * 1024];       // 64 KB, XOR-swizzled rows
  __shared__ float  pre[4][32][68];      // [kw][gate-row][batch] partials, ~34 KB
  __shared__ bf16_t xgs[2][64 * 32];     // xg slab ping-pong, 8 KB

  // --- load weight slab into LDS (swizzled) ---
  for (int idx = tid; idx < 4096; idx += 512) {
    int r = idx >> 7;            // 0..31
    int c = idx & 127;           // 8-elem chunk
    bf16x8 v = *(const bf16x8*)(Wh + (size_t)(b * 32 + r) * HID + c * 8);
    *(bf16x8*)((char*)Wt + r * 2048 + ((c * 16) ^ ((r & 7) << 4))) = v;
  }
  // --- prefetch xg for t=0 ---
  if (tid < 256) {
    int batch = tid >> 2, c = tid & 3;
    bf16x8 v = *(const bf16x8*)(xg + (size_t)batch * NGATE + b * 32 + c * 8);
    *(bf16x8*)(xgs[0] + batch * 32 + c * 8) = v;
  }
  __syncthreads();

  // elementwise ownership: thread (tid<256) owns (batch = tid>>2, j = b*8 + (tid&3)*2 .. +1)
  float c0 = 0.f, c1 = 0.f;

  for (int t = 0; t < SEQLEN; ++t) {
    // prefetch next xg slab into regs (hidden under the K-loop latency)
    bf16x8 xnext;
    if (t < SEQLEN - 1 && tid < 256) {
      int batch = tid >> 2, c = tid & 3;
      xnext = *(const bf16x8*)(xg + (size_t)(t + 1) * NBATCH * NGATE + (size_t)batch * NGATE + b * 32 + c * 8);
    }

    const bf16_t* hp = (const bf16_t*)hring + (size_t)(t & 1) * (NBATCH * HID);

    // full A preload: one latency exposure, then MFMA-bound
    bf16x8 af[8][4];
#pragma unroll
    for (int kk = 0; kk < 8; ++kk)
#pragma unroll
      for (int mi = 0; mi < 4; ++mi)
        af[kk][mi] = *(const bf16x8*)(hp + (size_t)(mi * 16 + arow) * HID + kbase + kk * 32 + kg);

    f32x4 acc[4] = {};
#pragma unroll
    for (int kk = 0; kk < 8; ++kk) {
      const int kb = kbase + kk * 32;
      bf16x8 bfr = *(const bf16x8*)((const char*)Wt + brow * 2048 + (((kb + kg) << 1) ^ ((brow & 7) << 4)));
#pragma unroll
      for (int mi = 0; mi < 4; ++mi)
        acc[mi] = __builtin_amdgcn_mfma_f32_16x16x32_bf16(af[kk][mi], bfr, acc[mi], 0, 0, 0);
    }

    // partial sums -> LDS
#pragma unroll
    for (int mi = 0; mi < 4; ++mi)
      *(f32x4*)&pre[kw][brow][mi * 16 + (l >> 4) * 4] = acc[mi];

    // stage next xg slab
    if (t < SEQLEN - 1 && tid < 256) {
      int batch = tid >> 2, c = tid & 3;
      *(bf16x8*)(xgs[(t + 1) & 1] + batch * 32 + c * 8) = xnext;
    }
    __syncthreads();

    // fused elementwise gate update (threads 0..255; 2 adjacent j per thread)
    if (tid < 256) {
      const int batch = tid >> 2, jp = (tid & 3) * 2;
      const bf16_t* xr = xgs[t & 1];
      float hv[2], cf[2];
#pragma unroll
      for (int it = 0; it < 2; ++it) {
        const int jj = jp + it;
        float pf = (float)xr[batch * 32 + jj];
        float pi = (float)xr[batch * 32 + 8 + jj];
        float po = (float)xr[batch * 32 + 16 + jj];
        float pc = (float)xr[batch * 32 + 24 + jj];
#pragma unroll
        for (int q = 0; q < 4; ++q) {
          pf += pre[q][jj][batch];
          pi += pre[q][8 + jj][batch];
          po += pre[q][16 + jj][batch];
          pc += pre[q][24 + jj][batch];
        }
        float fg = 1.f / (1.f + __expf(-pf));
        float ig = 1.f / (1.f + __expf(-pi));
        float og = 1.f / (1.f + __expf(-po));
        float e2 = __expf(-2.f * fabsf(pc));
        float gg = __builtin_copysignf((1.f - e2) / (1.f + e2), pc);
        float& cs = it ? c1 : c0;
        cs = fg * cs + ig * gg;
        float e2c = __expf(-2.f * fabsf(cs));
        float th = __builtin_copysignf((1.f - e2c) / (1.f + e2c), cs);
        hv[it] = og * th;
        cf[it] = cs;
      }
      const int j0 = b * 8 + jp;
      // h_seq (fp32, plain store — flushed at kernel end)
      *(float2*)(out + ((size_t)t * NBATCH + batch) * HID + j0) = make_float2(hv[0], hv[1]);
      // h for next step: write-through packed bf16 pair via agent-scope atomic (lands at coherence point)
      unsigned int pk = (unsigned int)__builtin_bit_cast(unsigned short, (bf16_t)hv[0]) |
                        ((unsigned int)__builtin_bit_cast(unsigned short, (bf16_t)hv[1]) << 16);
      unsigned int* hdst = hring + (size_t)((t + 1) & 1) * (NBATCH * HID / 2) + batch * (HID / 2) + (j0 >> 1);
      unsigned int old = __hip_atomic_exchange(hdst, pk, __ATOMIC_RELAXED, __HIP_MEMORY_SCOPE_AGENT);
      asm volatile("" :: "v"(old));  // keep returning form (completion = performed at IC)
      if (t == SEQLEN - 1) {
        *(float2*)(out + (size_t)SEQLEN * NBATCH * HID + (size_t)batch * HID + j0) = make_float2(hv[0], hv[1]);
        *(float2*)(out + (size_t)SEQLEN * NBATCH * HID + (size_t)NBATCH * HID + (size_t)batch * HID + j0) = make_float2(cf[0], cf[1]);
      }
    }

    // grid-wide flag: syncthreads drains all waves' vmcnt (atomics acked at IC) before tid0 adds
    if (t < SEQLEN - 1) {
      __syncthreads();
      if (tid == 0) {
        __builtin_amdgcn_fence(__ATOMIC_ACQUIRE, "agent");   // buffer_inv (L1+L2 tag clear, no writeback)
        __hip_atomic_fetch_add(ctr, 1, __ATOMIC_RELAXED, __HIP_MEMORY_SCOPE_AGENT);
        int target = NBLK * (t + 1);
        while (__hip_atomic_load(ctr, __ATOMIC_RELAXED, __HIP_MEMORY_SCOPE_AGENT) < target)
          __builtin_amdgcn_s_sleep(1);
      }
      __syncthreads();
    }
  }
}

extern "C" void kernel_launch(void* const* d_in, const int* in_sizes, int n_in,
                              void* d_out, int out_size, void* d_ws, size_t ws_size,
                              hipStream_t stream) {
  (void)in_sizes; (void)n_in; (void)out_size; (void)ws_size;
  char* ws = (char*)d_ws;
  bf16_t* xg  = (bf16_t*)(ws + XG_OFF);
  bf16_t* xbf = (bf16_t*)(ws + XBF_OFF);
  bf16_t* Wx  = (bf16_t*)(ws + WX_OFF);
  bf16_t* Wh  = (bf16_t*)(ws + WH_OFF);
  float*  bs  = (float*)(ws + BS_OFF);
  unsigned int* hring = (unsigned int*)(ws + HBF_OFF);
  int*    ctr = (int*)(ws + CTR_OFF);

  const float* x = (const float*)d_in[0];
  GatePtrs p;
  for (int g = 0; g < 4; ++g) {
    p.Wi[g] = (const float*)d_in[1 + 4 * g];
    p.bi[g] = (const float*)d_in[2 + 4 * g];
    p.Wh[g] = (const float*)d_in[3 + 4 * g];
    p.bh[g] = (const float*)d_in[4 + 4 * g];
  }

  hipMemsetAsync(hring, 0, 2 * NBATCH * HID * sizeof(bf16_t), stream);
  hipMemsetAsync(ctr, 0, 64, stream);
  pack_x_k<<<4096, 256, 0, stream>>>(x, xbf);
  pack_w_k<<<3072, 256, 0, stream>>>(p, Wx, Wh, bs);
  gemm_xproj_k<<<dim3(32, 128), 256, 0, stream>>>(xbf, Wx, bs, xg);
  lstm_rec_k<<<NBLK, 512, 0, stream>>>(Wh, xg, hring, (float*)d_out, ctr);
}

// Round 3
// 2764.586 us; speedup vs baseline: 1.7346x; 1.0726x over previous
//
#include <hip/hip_runtime.h>
#include <hip/hip_bf16.h>

typedef __bf16 bf16_t;
typedef __bf16 bf16x8 __attribute__((ext_vector_type(8)));
typedef float f32x4 __attribute__((ext_vector_type(4)));

#define SEQLEN 256
#define NBATCH 64
#define INDIM  512
#define HID    1024
#define NGATE  4096
#define NBLK   128

// workspace layout (bytes)
#define XG_OFF   0ull                // bf16 [16384][4096]  = 134217728
#define XBF_OFF  134217728ull        // bf16 [16384][512]   = 16777216 (dead after gemm; fallback h-ring)
#define WX_OFF   150994944ull        // bf16 [4096][512]    = 4194304
#define WH_OFF   155189248ull        // bf16 [4096][1024]   = 8388608
#define BS_OFF   163577856ull        // f32  [4096]         = 16384
#define CTR_OFF  163594240ull        // int barrier counter (256 B reserved)
#define HSEQ_OFF 163594496ull        // bf16 [257][64][1024] = 33685504 (write-once h slots)
#define SLOT_ELEMS (NBATCH * HID)    // 65536 bf16 = 131072 B per slot
#define SLOT_BYTES 131072ull

__device__ __forceinline__ bf16x8 cvt8(float4 a, float4 b) {
  bf16x8 v;
  v[0] = (bf16_t)a.x; v[1] = (bf16_t)a.y; v[2] = (bf16_t)a.z; v[3] = (bf16_t)a.w;
  v[4] = (bf16_t)b.x; v[5] = (bf16_t)b.y; v[6] = (bf16_t)b.z; v[7] = (bf16_t)b.w;
  return v;
}

// ---------------- pack x -> bf16 ----------------
__global__ __launch_bounds__(256) void pack_x_k(const float* __restrict__ x,
                                                bf16_t* __restrict__ xb) {
  int idx = blockIdx.x * 256 + threadIdx.x;       // 8 elems each
  const float4* s = (const float4*)x + (size_t)idx * 2;
  float4 a = s[0], b = s[1];
  *(bf16x8*)(xb + (size_t)idx * 8) = cvt8(a, b);
}

// ---------------- pack weights (gate-permuted rows) + bias sums ----------------
struct GatePtrs {
  const float* Wi[4];
  const float* bi[4];
  const float* Wh[4];
  const float* bh[4];
};

__global__ __launch_bounds__(256) void pack_w_k(GatePtrs p,
                                                bf16_t* __restrict__ Wx,
                                                bf16_t* __restrict__ Wh,
                                                float* __restrict__ bsum) {
  int idx = blockIdx.x * 256 + threadIdx.x;       // 0 .. 786431
  int row = idx / 192;                            // n_packed, 0..4095
  int c   = idx % 192;
  int blk = row >> 5, r = row & 31, g = r >> 3, jj = r & 7;
  int j = blk * 8 + jj;                           // original hidden index
  if (c == 0) bsum[row] = p.bi[g][j] + p.bh[g][j];
  if (c < 64) {
    const float4* s = (const float4*)(p.Wi[g] + (size_t)j * INDIM + c * 8);
    *(bf16x8*)(Wx + (size_t)row * INDIM + c * 8) = cvt8(s[0], s[1]);
  } else {
    int cc = c - 64;
    const float4* s = (const float4*)(p.Wh[g] + (size_t)j * HID + cc * 8);
    *(bf16x8*)(Wh + (size_t)row * HID + cc * 8) = cvt8(s[0], s[1]);
  }
}

// ---------------- phase 1: xg = x @ Wx^T + bsum (bf16 out) ----------------
__global__ __launch_bounds__(256) void gemm_xproj_k(const bf16_t* __restrict__ A,
                                                    const bf16_t* __restrict__ B,
                                                    const float* __restrict__ bsum,
                                                    bf16_t* __restrict__ C) {
  __shared__ bf16_t As[128 * 32];
  __shared__ bf16_t Bs[128 * 32];
  const int tid = threadIdx.x, w = tid >> 6, l = tid & 63;
  const int m0 = blockIdx.y * 128, n0 = blockIdx.x * 128;
  const int wr = (w >> 1) * 64, wc = (w & 1) * 64;
  const int kg = (l >> 4) * 8, rr = l & 15;
  f32x4 acc[4][4] = {};

  const int segrow = l >> 2, segk = (l & 3) * 8;
  for (int k0 = 0; k0 < INDIM; k0 += 32) {
    __syncthreads();
#pragma unroll
    for (int i = 0; i < 2; ++i) {
      int seg = w * 2 + i;
      const bf16_t* ga = A + (size_t)(m0 + seg * 16 + segrow) * INDIM + k0 + segk;
      __builtin_amdgcn_global_load_lds((const __attribute__((address_space(1))) void*)ga,
                                       (__attribute__((address_space(3))) void*)(As + seg * 512),
                                       16, 0, 0);
      const bf16_t* gb = B + (size_t)(n0 + seg * 16 + segrow) * INDIM + k0 + segk;
      __builtin_amdgcn_global_load_lds((const __attribute__((address_space(1))) void*)gb,
                                       (__attribute__((address_space(3))) void*)(Bs + seg * 512),
                                       16, 0, 0);
    }
    __syncthreads();
    bf16x8 af[4], bfr[4];
#pragma unroll
    for (int mi = 0; mi < 4; ++mi) af[mi]  = *(const bf16x8*)(As + (wr + mi * 16 + rr) * 32 + kg);
#pragma unroll
    for (int ni = 0; ni < 4; ++ni) bfr[ni] = *(const bf16x8*)(Bs + (wc + ni * 16 + rr) * 32 + kg);
#pragma unroll
    for (int mi = 0; mi < 4; ++mi)
#pragma unroll
      for (int ni = 0; ni < 4; ++ni)
        acc[mi][ni] = __builtin_amdgcn_mfma_f32_16x16x32_bf16(af[mi], bfr[ni], acc[mi][ni], 0, 0, 0);
  }
  const int ri = (l >> 4) * 4;
#pragma unroll
  for (int ni = 0; ni < 4; ++ni) {
    int n = n0 + wc + ni * 16 + rr;
    float bs = bsum[n];
#pragma unroll
    for (int mi = 0; mi < 4; ++mi) {
      int mbase = m0 + wr + mi * 16 + ri;
#pragma unroll
      for (int r = 0; r < 4; ++r)
        C[(size_t)(mbase + r) * NGATE + n] = (bf16_t)(acc[mi][ni][r] + bs);
    }
  }
}

// ---------------- phase 2: persistent recurrence ----------------
// 128 blocks x 512 threads. Block b owns gate-rows [b*32, b*32+32) == h columns [b*8, b*8+8).
// 8 waves: kw = w>>1 (K slice of 256), nw = w&1 (16 gate-rows each).
// h(t+1) published write-through (agent-scope atomic store -> IC). When R==257 each slot is
// write-once within the dispatch -> plain cacheable reads are never stale (dispatch-entry
// invalidate covers replays) -> NO fences. Fallback (small ws): ring + per-step acquire fence.
__global__ __launch_bounds__(512, 1) void lstm_rec_k(const bf16_t* __restrict__ Wh,
                                                     const bf16_t* __restrict__ xg,
                                                     bf16_t* __restrict__ hseq,
                                                     float* __restrict__ out,
                                                     int* __restrict__ ctr,
                                                     int R, int use_fence) {
  const int b = blockIdx.x;
  const int tid = threadIdx.x;
  const int w = tid >> 6, l = tid & 63;
  const int kw = w >> 1, nw = w & 1;
  const int arow = l & 15, kg = (l >> 4) * 8;
  const int kbase = kw * 256;
  const int brow = nw * 16 + arow;

  __shared__ bf16_t Wt[32 * 1024];       // 64 KB, XOR-swizzled rows
  __shared__ float  pre[4][32][68];      // [kw][gate-row][batch] partials
  __shared__ bf16_t xgs[2][64 * 32];     // xg slab ping-pong

  // --- load weight slab into LDS (swizzled) ---
  for (int idx = tid; idx < 4096; idx += 512) {
    int r = idx >> 7;
    int c = idx & 127;
    bf16x8 v = *(const bf16x8*)(Wh + (size_t)(b * 32 + r) * HID + c * 8);
    *(bf16x8*)((char*)Wt + r * 2048 + ((c * 16) ^ ((r & 7) << 4))) = v;
  }
  // --- prefetch xg for t=0 ---
  if (tid < 256) {
    int batch = tid >> 2, c = tid & 3;
    bf16x8 v = *(const bf16x8*)(xg + (size_t)batch * NGATE + b * 32 + c * 8);
    *(bf16x8*)(xgs[0] + batch * 32 + c * 8) = v;
  }
  __syncthreads();

  float c0 = 0.f, c1 = 0.f;

  for (int t = 0; t < SEQLEN; ++t) {
    // prefetch next xg slab into regs (in flight across the whole step)
    bf16x8 xnext;
    if (t < SEQLEN - 1 && tid < 256) {
      int batch = tid >> 2, c = tid & 3;
      xnext = *(const bf16x8*)(xg + (size_t)(t + 1) * NBATCH * NGATE + (size_t)batch * NGATE + b * 32 + c * 8);
    }

    const bf16_t* hp = hseq + (size_t)(t % R) * SLOT_ELEMS;

    // full A preload: issue all 32 loads, force materialization -> one latency exposure
    bf16x8 af[8][4];
#pragma unroll
    for (int kk = 0; kk < 8; ++kk)
#pragma unroll
      for (int mi = 0; mi < 4; ++mi)
        af[kk][mi] = *(const bf16x8*)(hp + (size_t)(mi * 16 + arow) * HID + kbase + kk * 32 + kg);
#pragma unroll
    for (int kk = 0; kk < 8; ++kk)
#pragma unroll
      for (int mi = 0; mi < 4; ++mi)
        asm volatile("" : "+v"(af[kk][mi]));

    f32x4 acc[4] = {};
#pragma unroll
    for (int kk = 0; kk < 8; ++kk) {
      const int kb = kbase + kk * 32;
      bf16x8 bfr = *(const bf16x8*)((const char*)Wt + brow * 2048 + (((kb + kg) << 1) ^ ((brow & 7) << 4)));
#pragma unroll
      for (int mi = 0; mi < 4; ++mi)
        acc[mi] = __builtin_amdgcn_mfma_f32_16x16x32_bf16(af[kk][mi], bfr, acc[mi], 0, 0, 0);
    }

    // partial sums -> LDS
#pragma unroll
    for (int mi = 0; mi < 4; ++mi)
      *(f32x4*)&pre[kw][brow][mi * 16 + (l >> 4) * 4] = acc[mi];

    // stage next xg slab
    if (t < SEQLEN - 1 && tid < 256) {
      int batch = tid >> 2, c = tid & 3;
      *(bf16x8*)(xgs[(t + 1) & 1] + batch * 32 + c * 8) = xnext;
    }
    __syncthreads();

    // fused elementwise gate update (threads 0..255; 2 adjacent j per thread)
    if (tid < 256) {
      const int batch = tid >> 2, jp = (tid & 3) * 2;
      const bf16_t* xr = xgs[t & 1];
      float hv[2], cf[2];
#pragma unroll
      for (int it = 0; it < 2; ++it) {
        const int jj = jp + it;
        float pf = (float)xr[batch * 32 + jj];
        float pi = (float)xr[batch * 32 + 8 + jj];
        float po = (float)xr[batch * 32 + 16 + jj];
        float pc = (float)xr[batch * 32 + 24 + jj];
#pragma unroll
        for (int q = 0; q < 4; ++q) {
          pf += pre[q][jj][batch];
          pi += pre[q][8 + jj][batch];
          po += pre[q][16 + jj][batch];
          pc += pre[q][24 + jj][batch];
        }
        float fg = 1.f / (1.f + __expf(-pf));
        float ig = 1.f / (1.f + __expf(-pi));
        float og = 1.f / (1.f + __expf(-po));
        float e2 = __expf(-2.f * fabsf(pc));
        float gg = __builtin_copysignf((1.f - e2) / (1.f + e2), pc);
        float& cs = it ? c1 : c0;
        cs = fg * cs + ig * gg;
        float e2c = __expf(-2.f * fabsf(cs));
        float th = __builtin_copysignf((1.f - e2c) / (1.f + e2c), cs);
        hv[it] = og * th;
        cf[it] = cs;
      }
      const int j0 = b * 8 + jp;
      *(float2*)(out + ((size_t)t * NBATCH + batch) * HID + j0) = make_float2(hv[0], hv[1]);
      // publish h(t+1): write-through packed bf16 pair (performed at IC)
      unsigned int pk = (unsigned int)__builtin_bit_cast(unsigned short, (bf16_t)hv[0]) |
                        ((unsigned int)__builtin_bit_cast(unsigned short, (bf16_t)hv[1]) << 16);
      unsigned int* hd = (unsigned int*)(hseq + (size_t)((t + 1) % R) * SLOT_ELEMS) + batch * (HID / 2) + (j0 >> 1);
      __hip_atomic_store(hd, pk, __ATOMIC_RELAXED, __HIP_MEMORY_SCOPE_AGENT);
      if (t == SEQLEN - 1) {
        *(float2*)(out + (size_t)SEQLEN * NBATCH * HID + (size_t)batch * HID + j0) = make_float2(hv[0], hv[1]);
        *(float2*)(out + (size_t)SEQLEN * NBATCH * HID + (size_t)NBATCH * HID + (size_t)batch * HID + j0) = make_float2(cf[0], cf[1]);
      }
    }

    // grid-wide flag: __syncthreads drains vmcnt (h stores performed at IC) before tid0 adds
    if (t < SEQLEN - 1) {
      __syncthreads();
      if (tid == 0) {
        if (use_fence)
          __builtin_amdgcn_fence(__ATOMIC_ACQUIRE, "agent");   // ring mode only: L1/L2 inv
        __hip_atomic_fetch_add(ctr, 1, __ATOMIC_RELAXED, __HIP_MEMORY_SCOPE_AGENT);
        int target = NBLK * (t + 1);
        while (__hip_atomic_load(ctr, __ATOMIC_RELAXED, __HIP_MEMORY_SCOPE_AGENT) < target)
          __builtin_amdgcn_s_sleep(1);
      }
      __syncthreads();
    }
  }
}

extern "C" void kernel_launch(void* const* d_in, const int* in_sizes, int n_in,
                              void* d_out, int out_size, void* d_ws, size_t ws_size,
                              hipStream_t stream) {
  (void)in_sizes; (void)n_in; (void)out_size;
  char* ws = (char*)d_ws;
  bf16_t* xg  = (bf16_t*)(ws + XG_OFF);
  bf16_t* xbf = (bf16_t*)(ws + XBF_OFF);
  bf16_t* Wx  = (bf16_t*)(ws + WX_OFF);
  bf16_t* Wh  = (bf16_t*)(ws + WH_OFF);
  float*  bs  = (float*)(ws + BS_OFF);
  int*    ctr = (int*)(ws + CTR_OFF);

  // choose h-slot layout: 257 write-once slots (fence-free) if ws allows,
  // else 128-slot ring in the dead xbf region with per-step acquire fence.
  bf16_t* hseq;
  int R, use_fence;
  if (ws_size >= HSEQ_OFF + 257ull * SLOT_BYTES) {
    hseq = (bf16_t*)(ws + HSEQ_OFF); R = 257; use_fence = 0;
  } else {
    hseq = (bf16_t*)(ws + XBF_OFF);  R = 128; use_fence = 1;  // xbf dead after gemm
  }

  const float* x = (const float*)d_in[0];
  GatePtrs p;
  for (int g = 0; g < 4; ++g) {
    p.Wi[g] = (const float*)d_in[1 + 4 * g];
    p.bi[g] = (const float*)d_in[2 + 4 * g];
    p.Wh[g] = (const float*)d_in[3 + 4 * g];
    p.bh[g] = (const float*)d_in[4 + 4 * g];
  }

  hipMemsetAsync(ctr, 0, 256, stream);
  pack_x_k<<<4096, 256, 0, stream>>>(x, xbf);
  pack_w_k<<<3072, 256, 0, stream>>>(p, Wx, Wh, bs);
  gemm_xproj_k<<<dim3(32, 128), 256, 0, stream>>>(xbf, Wx, bs, xg);
  // zero h(0) slot AFTER gemm in case hseq aliases xbf (fallback mode)
  hipMemsetAsync(hseq, 0, SLOT_BYTES, stream);
  lstm_rec_k<<<NBLK, 512, 0, stream>>>(Wh, xg, hseq, (float*)d_out, ctr, R, use_fence);
}

// Round 4
// 2515.546 us; speedup vs baseline: 1.9064x; 1.0990x over previous
//
#include <hip/hip_runtime.h>
#include <hip/hip_bf16.h>

typedef __bf16 bf16_t;
typedef __bf16 bf16x8 __attribute__((ext_vector_type(8)));
typedef float f32x4 __attribute__((ext_vector_type(4)));
typedef int   i32x4 __attribute__((ext_vector_type(4)));

#define SEQLEN 256
#define NBATCH 64
#define INDIM  512
#define HID    1024
#define NGATE  4096
#define NBLK   128

// workspace layout (bytes)
#define XG_OFF   0ull                // bf16 [16384][4096]  = 134217728
#define XBF_OFF  134217728ull        // bf16 [16384][512]   = 16777216 (dead after gemm; fallback h-ring = 128 slots exactly)
#define WX_OFF   150994944ull        // bf16 [4096][512]    = 4194304  (dead after gemm; ARR flags overlay, 2 MB)
#define WH_OFF   155189248ull        // bf16 [4096][1024]   = 8388608
#define BS_OFF   163577856ull        // f32  [4096]         = 16384
#define HSEQ_OFF 163594240ull        // bf16 [257][64][1024] = 33685504 (primary write-once h slots)
#define SLOT_ELEMS (NBATCH * HID)    // 65536 bf16 = 131072 B per slot
#define SLOT_BYTES 131072ull
#define PRIMARY_WS_NEED (HSEQ_OFF + 257ull * SLOT_BYTES)   // 197279744

__device__ __forceinline__ bf16x8 cvt8(float4 a, float4 b) {
  bf16x8 v;
  v[0] = (bf16_t)a.x; v[1] = (bf16_t)a.y; v[2] = (bf16_t)a.z; v[3] = (bf16_t)a.w;
  v[4] = (bf16_t)b.x; v[5] = (bf16_t)b.y; v[6] = (bf16_t)b.z; v[7] = (bf16_t)b.w;
  return v;
}

// ---------------- pack x -> bf16 ----------------
__global__ __launch_bounds__(256) void pack_x_k(const float* __restrict__ x,
                                                bf16_t* __restrict__ xb) {
  int idx = blockIdx.x * 256 + threadIdx.x;
  const float4* s = (const float4*)x + (size_t)idx * 2;
  float4 a = s[0], b = s[1];
  *(bf16x8*)(xb + (size_t)idx * 8) = cvt8(a, b);
}

// ---------------- pack weights (gate-permuted rows) + bias sums ----------------
struct GatePtrs {
  const float* Wi[4];
  const float* bi[4];
  const float* Wh[4];
  const float* bh[4];
};

__global__ __launch_bounds__(256) void pack_w_k(GatePtrs p,
                                                bf16_t* __restrict__ Wx,
                                                bf16_t* __restrict__ Wh,
                                                float* __restrict__ bsum) {
  int idx = blockIdx.x * 256 + threadIdx.x;       // 0 .. 786431
  int row = idx / 192;                            // n_packed, 0..4095
  int c   = idx % 192;
  int blk = row >> 5, r = row & 31, g = r >> 3, jj = r & 7;
  int j = blk * 8 + jj;
  if (c == 0) bsum[row] = p.bi[g][j] + p.bh[g][j];
  if (c < 64) {
    const float4* s = (const float4*)(p.Wi[g] + (size_t)j * INDIM + c * 8);
    *(bf16x8*)(Wx + (size_t)row * INDIM + c * 8) = cvt8(s[0], s[1]);
  } else {
    int cc = c - 64;
    const float4* s = (const float4*)(p.Wh[g] + (size_t)j * HID + cc * 8);
    *(bf16x8*)(Wh + (size_t)row * HID + cc * 8) = cvt8(s[0], s[1]);
  }
}

// ---------------- phase 1: xg = x @ Wx^T + bsum (bf16 out) ----------------
__global__ __launch_bounds__(256) void gemm_xproj_k(const bf16_t* __restrict__ A,
                                                    const bf16_t* __restrict__ B,
                                                    const float* __restrict__ bsum,
                                                    bf16_t* __restrict__ C) {
  __shared__ bf16_t As[128 * 32];
  __shared__ bf16_t Bs[128 * 32];
  const int tid = threadIdx.x, w = tid >> 6, l = tid & 63;
  const int m0 = blockIdx.y * 128, n0 = blockIdx.x * 128;
  const int wr = (w >> 1) * 64, wc = (w & 1) * 64;
  const int kg = (l >> 4) * 8, rr = l & 15;
  f32x4 acc[4][4] = {};

  const int segrow = l >> 2, segk = (l & 3) * 8;
  for (int k0 = 0; k0 < INDIM; k0 += 32) {
    __syncthreads();
#pragma unroll
    for (int i = 0; i < 2; ++i) {
      int seg = w * 2 + i;
      const bf16_t* ga = A + (size_t)(m0 + seg * 16 + segrow) * INDIM + k0 + segk;
      __builtin_amdgcn_global_load_lds((const __attribute__((address_space(1))) void*)ga,
                                       (__attribute__((address_space(3))) void*)(As + seg * 512),
                                       16, 0, 0);
      const bf16_t* gb = B + (size_t)(n0 + seg * 16 + segrow) * INDIM + k0 + segk;
      __builtin_amdgcn_global_load_lds((const __attribute__((address_space(1))) void*)gb,
                                       (__attribute__((address_space(3))) void*)(Bs + seg * 512),
                                       16, 0, 0);
    }
    __syncthreads();
    bf16x8 af[4], bfr[4];
#pragma unroll
    for (int mi = 0; mi < 4; ++mi) af[mi]  = *(const bf16x8*)(As + (wr + mi * 16 + rr) * 32 + kg);
#pragma unroll
    for (int ni = 0; ni < 4; ++ni) bfr[ni] = *(const bf16x8*)(Bs + (wc + ni * 16 + rr) * 32 + kg);
#pragma unroll
    for (int mi = 0; mi < 4; ++mi)
#pragma unroll
      for (int ni = 0; ni < 4; ++ni)
        acc[mi][ni] = __builtin_amdgcn_mfma_f32_16x16x32_bf16(af[mi], bfr[ni], acc[mi][ni], 0, 0, 0);
  }
  const int ri = (l >> 4) * 4;
#pragma unroll
  for (int ni = 0; ni < 4; ++ni) {
    int n = n0 + wc + ni * 16 + rr;
    float bs = bsum[n];
#pragma unroll
    for (int mi = 0; mi < 4; ++mi) {
      int mbase = m0 + wr + mi * 16 + ri;
#pragma unroll
      for (int r = 0; r < 4; ++r)
        C[(size_t)(mbase + r) * NGATE + n] = (bf16_t)(acc[mi][ni][r] + bs);
    }
  }
}

// forced global loads (cannot be sunk/re-rolled by the compiler)
#define GLD_P(dst, ptr, OFF) \
  asm volatile("global_load_dwordx4 %0, %1, off offset:" OFF : "=v"(dst) : "v"(ptr))
#define GLD_C(dst, ptr, OFF) \
  asm volatile("global_load_dwordx4 %0, %1, off offset:" OFF " sc0 sc1" : "=v"(dst) : "v"(ptr))
#define GLD8_P(d, ptr) \
  GLD_P(d[0], ptr, "0");   GLD_P(d[1], ptr, "64");  GLD_P(d[2], ptr, "128"); GLD_P(d[3], ptr, "192"); \
  GLD_P(d[4], ptr, "256"); GLD_P(d[5], ptr, "320"); GLD_P(d[6], ptr, "384"); GLD_P(d[7], ptr, "448")
#define GLD8_C(d, ptr) \
  GLD_C(d[0], ptr, "0");   GLD_C(d[1], ptr, "64");  GLD_C(d[2], ptr, "128"); GLD_C(d[3], ptr, "192"); \
  GLD_C(d[4], ptr, "256"); GLD_C(d[5], ptr, "320"); GLD_C(d[6], ptr, "384"); GLD_C(d[7], ptr, "448")

// ---------------- phase 2: persistent recurrence ----------------
// 128 blocks x 512 threads. Block b owns gate-rows [b*32, b*32+32) == h cols [b*8, b*8+8).
// Waves 0-7: (kw = w>>1) K-quarter, (nw = w&1) 16 gate-rows. COHERENT=0: write-once h slots,
// plain cacheable loads (freshness: slot never touched before its producer's WT store).
// COHERENT=1: 128-slot ring, sc0/sc1 cache-bypass loads. Both fence-free.
// Barrier: per-step write-once arrival flags, one store per block, per-lane distributed polling.
template<int COHERENT>
__global__ __launch_bounds__(512, 2) void lstm_rec_k(const bf16_t* __restrict__ Wh,
                                                     const bf16_t* __restrict__ xg,
                                                     bf16_t* __restrict__ hseq,
                                                     float* __restrict__ out,
                                                     int* __restrict__ arr,
                                                     int R) {
  const int b = blockIdx.x;
  const int tid = threadIdx.x;
  const int w = tid >> 6, l = tid & 63;
  const int kw = w >> 1, nw = w & 1;
  const int arow = l & 15, kg = (l >> 4) * 8;
  const int kbase = kw * 256;
  const int brow = nw * 16 + arow;

  __shared__ bf16_t Wt[32 * 1024];       // 64 KB, XOR-swizzled rows
  __shared__ float  pre[4][32][68];      // [kw][gate-row][batch] partials
  __shared__ bf16_t xgs[2][64 * 32];     // xg slab ping-pong

  for (int idx = tid; idx < 4096; idx += 512) {
    int r = idx >> 7;
    int c = idx & 127;
    bf16x8 v = *(const bf16x8*)(Wh + (size_t)(b * 32 + r) * HID + c * 8);
    *(bf16x8*)((char*)Wt + r * 2048 + ((c * 16) ^ ((r & 7) << 4))) = v;
  }
  if (tid < 256) {
    int batch = tid >> 2, c = tid & 3;
    bf16x8 v = *(const bf16x8*)(xg + (size_t)batch * NGATE + b * 32 + c * 8);
    *(bf16x8*)(xgs[0] + batch * 32 + c * 8) = v;
  }
  __syncthreads();

  // elementwise ownership: batch = tid>>3 (0..63), jj = tid&7; one cell-state each
  const int ebatch = tid >> 3, ejj = tid & 7;
  float cs = 0.f;

  for (int t = 0; t < SEQLEN; ++t) {
    // xg prefetch for t+1 (independent; rides alongside the h loads)
    bf16x8 xnext;
    if (t < SEQLEN - 1 && tid < 256) {
      int batch = tid >> 2, c = tid & 3;
      xnext = *(const bf16x8*)(xg + (size_t)(t + 1) * NBATCH * NGATE + (size_t)batch * NGATE + b * 32 + c * 8);
    }

    const bf16_t* hp = hseq + (size_t)(t % R) * SLOT_ELEMS;

    // ---- forced A preload: 32 asm loads in flight, one waitcnt ----
    i32x4 af[4][8];   // [mi][kk], statically indexed
    {
      const char* p0 = (const char*)(hp + (size_t)(0 * 16 + arow) * HID + kbase + kg);
      const char* p1 = (const char*)(hp + (size_t)(1 * 16 + arow) * HID + kbase + kg);
      const char* p2 = (const char*)(hp + (size_t)(2 * 16 + arow) * HID + kbase + kg);
      const char* p3 = (const char*)(hp + (size_t)(3 * 16 + arow) * HID + kbase + kg);
      if (COHERENT) {
        GLD8_C(af[0], p0); GLD8_C(af[1], p1); GLD8_C(af[2], p2); GLD8_C(af[3], p3);
      } else {
        GLD8_P(af[0], p0); GLD8_P(af[1], p1); GLD8_P(af[2], p2); GLD8_P(af[3], p3);
      }
    }
    asm volatile("s_waitcnt vmcnt(0)" ::: "memory");
    __builtin_amdgcn_sched_barrier(0);

    f32x4 acc[4] = {};
#pragma unroll
    for (int kk = 0; kk < 8; ++kk) {
      const int kb = kbase + kk * 32;
      bf16x8 bfr = *(const bf16x8*)((const char*)Wt + brow * 2048 + (((kb + kg) << 1) ^ ((brow & 7) << 4)));
#pragma unroll
      for (int mi = 0; mi < 4; ++mi)
        acc[mi] = __builtin_amdgcn_mfma_f32_16x16x32_bf16(__builtin_bit_cast(bf16x8, af[mi][kk]), bfr, acc[mi], 0, 0, 0);
    }

#pragma unroll
    for (int mi = 0; mi < 4; ++mi)
      *(f32x4*)&pre[kw][brow][mi * 16 + (l >> 4) * 4] = acc[mi];

    if (t < SEQLEN - 1 && tid < 256) {
      int batch = tid >> 2, c = tid & 3;
      *(bf16x8*)(xgs[(t + 1) & 1] + batch * 32 + c * 8) = xnext;
    }
    __syncthreads();

    // ---- fused elementwise (all 512 threads, 1 h element each) ----
    {
      const bf16_t* xr = xgs[t & 1];
      float pf = (float)xr[ebatch * 32 + ejj];
      float pi = (float)xr[ebatch * 32 + 8 + ejj];
      float po = (float)xr[ebatch * 32 + 16 + ejj];
      float pc = (float)xr[ebatch * 32 + 24 + ejj];
#pragma unroll
      for (int q = 0; q < 4; ++q) {
        pf += pre[q][ejj][ebatch];
        pi += pre[q][8 + ejj][ebatch];
        po += pre[q][16 + ejj][ebatch];
        pc += pre[q][24 + ejj][ebatch];
      }
      float fg = 1.f / (1.f + __expf(-pf));
      float ig = 1.f / (1.f + __expf(-pi));
      float og = 1.f / (1.f + __expf(-po));
      float e2 = __expf(-2.f * fabsf(pc));
      float gg = __builtin_copysignf((1.f - e2) / (1.f + e2), pc);
      cs = fg * cs + ig * gg;
      float e2c = __expf(-2.f * fabsf(cs));
      float th = __builtin_copysignf((1.f - e2c) / (1.f + e2c), cs);
      float hv = og * th;
      const int j = b * 8 + ejj;
      out[((size_t)t * NBATCH + ebatch) * HID + j] = hv;
      // publish h(t+1): 2B write-through agent store (ack = performed at IC)
      unsigned short hb = __builtin_bit_cast(unsigned short, (bf16_t)hv);
      unsigned short* hd = (unsigned short*)(hseq + (size_t)((t + 1) % R) * SLOT_ELEMS) + ebatch * HID + j;
      __hip_atomic_store(hd, hb, __ATOMIC_RELAXED, __HIP_MEMORY_SCOPE_AGENT);
      if (t == SEQLEN - 1) {
        out[(size_t)SEQLEN * NBATCH * HID + (size_t)ebatch * HID + j] = hv;
        out[(size_t)SEQLEN * NBATCH * HID + (size_t)NBATCH * HID + (size_t)ebatch * HID + j] = cs;
      }
    }

    // ---- distributed grid barrier ----
    if (t < SEQLEN - 1) {
      __syncthreads();   // per-wave vmcnt(0) drain: all WT h-stores performed at IC
      if (tid == 0)
        __hip_atomic_store(&arr[(t * NBLK + b) * 16], t + 1, __ATOMIC_RELAXED, __HIP_MEMORY_SCOPE_AGENT);
      if (tid >= 384) {
        const int blk = tid - 384;       // each lane watches one block's flag
        while (__hip_atomic_load(&arr[(t * NBLK + blk) * 16], __ATOMIC_RELAXED, __HIP_MEMORY_SCOPE_AGENT) != t + 1)
          __builtin_amdgcn_s_sleep(1);
      }
      __syncthreads();
      __builtin_amdgcn_sched_barrier(0);
    }
  }
}

extern "C" void kernel_launch(void* const* d_in, const int* in_sizes, int n_in,
                              void* d_out, int out_size, void* d_ws, size_t ws_size,
                              hipStream_t stream) {
  (void)in_sizes; (void)n_in; (void)out_size;
  char* ws = (char*)d_ws;
  bf16_t* xg  = (bf16_t*)(ws + XG_OFF);
  bf16_t* xbf = (bf16_t*)(ws + XBF_OFF);
  bf16_t* Wx  = (bf16_t*)(ws + WX_OFF);
  bf16_t* Wh  = (bf16_t*)(ws + WH_OFF);
  float*  bs  = (float*)(ws + BS_OFF);
  int*    arr = (int*)(ws + WX_OFF);    // Wx dead after gemm; 2 MB flag array

  const float* x = (const float*)d_in[0];
  GatePtrs p;
  for (int g = 0; g < 4; ++g) {
    p.Wi[g] = (const float*)d_in[1 + 4 * g];
    p.bi[g] = (const float*)d_in[2 + 4 * g];
    p.Wh[g] = (const float*)d_in[3 + 4 * g];
    p.bh[g] = (const float*)d_in[4 + 4 * g];
  }

  const bool primary = ws_size >= PRIMARY_WS_NEED;
  bf16_t* hseq = primary ? (bf16_t*)(ws + HSEQ_OFF) : (bf16_t*)(ws + XBF_OFF);
  const int R  = primary ? 257 : 128;

  pack_x_k<<<4096, 256, 0, stream>>>(x, xbf);
  pack_w_k<<<3072, 256, 0, stream>>>(p, Wx, Wh, bs);
  gemm_xproj_k<<<dim3(32, 128), 256, 0, stream>>>(xbf, Wx, bs, xg);
  // after gemm: Wx/xbf regions reusable
  hipMemsetAsync(arr, 0, 256 * NBLK * 64, stream);
  hipMemsetAsync(hseq, 0, SLOT_BYTES, stream);
  if (primary)
    lstm_rec_k<0><<<NBLK, 512, 0, stream>>>(Wh, xg, hseq, (float*)d_out, arr, R);
  else
    lstm_rec_k<1><<<NBLK, 512, 0, stream>>>(Wh, xg, hseq, (float*)d_out, arr, R);
}